// Round 1
// baseline (648.296 us; speedup 1.0000x reference)
//
#include <hip/hip_runtime.h>

// FractalDimension: out[row] = sum_{l=0}^{1023} in[row*1024 + l] / (l+1)
// rows = C*B*N = 131072, L = 1024, fp32 in/out.
// Memory-bound: 512 MB read @ ~6.3 TB/s -> ~81 us floor.

constexpr int kL = 1024;

__global__ __launch_bounds__(256) void FractalDimension_kernel(
    const float* __restrict__ in, float* __restrict__ out) {
  const int row = blockIdx.x;
  const int tid = threadIdx.x;

  // One float4 per thread covers the whole 1024-element row per block.
  const float4* p = reinterpret_cast<const float4*>(in + (size_t)row * kL);
  float4 v = p[tid];

  const float b0 = (float)(4 * tid + 1);
  float s = v.x / b0 + v.y / (b0 + 1.0f) + v.z / (b0 + 2.0f) + v.w / (b0 + 3.0f);

  // Wave-64 butterfly reduce.
  #pragma unroll
  for (int off = 32; off > 0; off >>= 1)
    s += __shfl_down(s, off, 64);

  __shared__ float partial[4];
  const int wave = tid >> 6;
  if ((tid & 63) == 0) partial[wave] = s;
  __syncthreads();

  if (tid == 0)
    out[row] = (partial[0] + partial[1]) + (partial[2] + partial[3]);
}

extern "C" void kernel_launch(void* const* d_in, const int* in_sizes, int n_in,
                              void* d_out, int out_size, void* d_ws, size_t ws_size,
                              hipStream_t stream) {
  const float* in = (const float*)d_in[0];
  float* out = (float*)d_out;
  const int rows = in_sizes[0] / kL;  // 131072
  FractalDimension_kernel<<<rows, 256, 0, stream>>>(in, out);
}